// Round 1
// baseline (125.878 us; speedup 1.0000x reference)
//
#include <hip/hip_runtime.h>

#define D_IN   1024
#define D_PROJ 256
#define N_C    64
#define N_ROWS 16384
#define BM     32
#define BK     64
#define A_STRIDE 72     // BK + 8 pad (bf16 elems) -> 144 B rows, uniform banks
#define Z_STRIDE 264    // D_PROJ + 8 pad -> 528 B rows

typedef float v4f __attribute__((ext_vector_type(4)));
typedef short v8s __attribute__((ext_vector_type(8)));

__device__ inline unsigned short f2bf(float f) {
  unsigned int u = __float_as_uint(f);
  u = u + 0x7fffu + ((u >> 16) & 1u);   // round-to-nearest-even
  return (unsigned short)(u >> 16);
}

__device__ inline void async16(const void* g, void* s) {
  __builtin_amdgcn_global_load_lds(
      (const __attribute__((address_space(1))) unsigned int*)g,
      (__attribute__((address_space(3))) unsigned int*)s, 16, 0, 0);
}

// ---------------------------------------------------------------------------
// Prep: projT bf16 [256][1024] (transposed), protoB bf16 [64][256], pnorm2[64]
// grid 80 x 256: blocks 0..63 transpose tiles, 64..79 protos
// ---------------------------------------------------------------------------
__global__ __launch_bounds__(256) void prep_kernel(
    const float* __restrict__ proj,      // [1024][256]
    const float* __restrict__ protos,    // [64][256]
    unsigned short* __restrict__ projT,  // [256][1024]
    unsigned short* __restrict__ protoB, // [64][256]
    float* __restrict__ pnorm2)          // [64]
{
  __shared__ float tile[64][65];
  const int b = blockIdx.x;
  const int t = threadIdx.x;
  if (b < 64) {
    const int k0 = (b & 15) * 64, n0 = (b >> 4) * 64;
    const int r = t >> 4, c4 = (t & 15) * 4;
    for (int rr = r; rr < 64; rr += 16) {
      const float4 v = *(const float4*)(proj + (k0 + rr) * D_PROJ + n0 + c4);
      tile[rr][c4 + 0] = v.x; tile[rr][c4 + 1] = v.y;
      tile[rr][c4 + 2] = v.z; tile[rr][c4 + 3] = v.w;
    }
    __syncthreads();
    const int n = t >> 2, kc = (t & 3) * 16;
    unsigned short o[16];
#pragma unroll
    for (int i = 0; i < 16; ++i) o[i] = f2bf(tile[kc + i][n]);
    unsigned short* dst = projT + (n0 + n) * D_IN + k0 + kc;
#pragma unroll
    for (int i = 0; i < 4; ++i) {
      ushort4 s4 = { o[4*i+0], o[4*i+1], o[4*i+2], o[4*i+3] };
      *(ushort4*)(dst + 4*i) = s4;
    }
  } else {
    const int w = t >> 6, l = t & 63;
    const int c = (b - 64) * 4 + w;                    // proto 0..63
    const float4 v = *(const float4*)(protos + c * D_PROJ + l * 4);
    float ss = v.x*v.x + v.y*v.y + v.z*v.z + v.w*v.w;
#pragma unroll
    for (int m = 1; m < 64; m <<= 1) ss += __shfl_xor(ss, m);
    if (l == 0) pnorm2[c] = ss;
    ushort4 o = { f2bf(v.x), f2bf(v.y), f2bf(v.z), f2bf(v.w) };
    *(ushort4*)(protoB + c * D_PROJ + l * 4) = o;
  }
}

// ---------------------------------------------------------------------------
// Main fused kernel: 32 rows/block, 512 blocks, 256 threads (4 waves)
// ---------------------------------------------------------------------------
__global__ __launch_bounds__(256) void protonet_main(
    const float* __restrict__ X,               // [16384][1024]
    const float* __restrict__ mean,            // [1024]
    const unsigned short* __restrict__ projT,  // [256][1024] bf16
    const unsigned short* __restrict__ protoB, // [64][256]   bf16
    const float* __restrict__ pnorm2,          // [64]
    float* __restrict__ out)                   // [16384][64]
{
  __shared__ unsigned short lds_A[BM * A_STRIDE];   // 4.6 KB, padded
  __shared__ unsigned short lds_B[D_PROJ * BK];     // 32 KB, swizzled; aliased as Z later
  __shared__ unsigned short lds_P[N_C * D_PROJ];    // 32 KB, swizzled
  __shared__ float lds_part[4][BM];
  __shared__ float lds_inv[BM];
  __shared__ float lds_z2[BM];

  const int t  = threadIdx.x;
  const int w  = t >> 6;
  const int l  = t & 63;
  const int q  = l >> 4;
  const int lc = l & 15;
  const int row0 = blockIdx.x * BM;

  // ---- stage protos -> LDS once (swizzled chunks: phys p holds logical p^(c&7)) ----
  {
    const int c0 = (w << 4) + (l >> 5);
    const int p  = l & 31;
#pragma unroll
    for (int s = 0; s < 8; ++s) {
      const int c = c0 + s * 2;
      async16(protoB + c * D_PROJ + ((p ^ (c & 7)) << 3),
              lds_P + (w * 4096 + s * 512));
    }
  }

  // per-lane invariant src index for B staging:
  // instr s: row n = 64w + 8s + (l>>3), phys chunk p = l&7, logical = p^(n&7)=p^((l>>3)&7)
  const int bsrc0 = ((w << 6) + (l >> 3)) * D_IN + (((l & 7) ^ ((l >> 3) & 7)) << 3);

  // A staging invariants: thread -> row ar, float4 slots aj and aj+8
  const int ar = t >> 3;
  const int aj = t & 7;
  const float* xbase = X + (row0 + ar) * D_IN + (aj << 2);
  const float* mbase = mean + (aj << 2);
  unsigned short* aw0 = lds_A + ar * A_STRIDE + (aj << 2);

  v4f acc[2][4];
#pragma unroll
  for (int i = 0; i < 2; ++i)
#pragma unroll
    for (int j = 0; j < 4; ++j) acc[i][j] = (v4f)(0.0f);

  for (int kt = 0; kt < D_IN / BK; ++kt) {
    const int k0 = kt * BK;
    __syncthreads();                       // previous compute done with LDS
    // B tile: [256][64] bf16 via global_load_lds (8 instrs/wave, 1 KB each)
#pragma unroll
    for (int s = 0; s < 8; ++s) {
      async16(projT + bsrc0 + s * (8 * D_IN) + k0,
              lds_B + (((w << 6) + (s << 3)) * BK));
    }
    // A tile: load fp32, center, convert, ds_write (padded)
    {
      const float4 x0 = *(const float4*)(xbase + k0);
      const float4 m0 = *(const float4*)(mbase + k0);
      const float4 x1 = *(const float4*)(xbase + k0 + 32);
      const float4 m1 = *(const float4*)(mbase + k0 + 32);
      ushort4 o0 = { f2bf(x0.x - m0.x), f2bf(x0.y - m0.y),
                     f2bf(x0.z - m0.z), f2bf(x0.w - m0.w) };
      ushort4 o1 = { f2bf(x1.x - m1.x), f2bf(x1.y - m1.y),
                     f2bf(x1.z - m1.z), f2bf(x1.w - m1.w) };
      *(ushort4*)(aw0)      = o0;
      *(ushort4*)(aw0 + 32) = o1;
    }
    __syncthreads();                       // drains vmcnt (B) + lgkm (A)
    // compute: 2 ksteps x (2 A-frag + 4 B-frag reads + 8 MFMA)
#pragma unroll
    for (int kk = 0; kk < 2; ++kk) {
      v8s a[2], bf[4];
#pragma unroll
      for (int i = 0; i < 2; ++i)
        a[i] = *(const v8s*)(lds_A + ((i << 4) + lc) * A_STRIDE + (kk << 5) + (q << 3));
#pragma unroll
      for (int j = 0; j < 4; ++j) {
        const int nb = (w << 6) + (j << 4) + lc;
        const int p  = ((kk << 2) + q) ^ (lc & 7);
        bf[j] = *(const v8s*)(lds_B + nb * BK + (p << 3));
      }
#pragma unroll
      for (int i = 0; i < 2; ++i)
#pragma unroll
        for (int j = 0; j < 4; ++j)
          acc[i][j] = __builtin_amdgcn_mfma_f32_16x16x32_bf16(a[i], bf[j], acc[i][j], 0, 0, 0);
    }
  }

  __syncthreads();                          // all reads of lds_B done
  // ---- Zraw -> LDS bf16 (reuse B region, padded stride) + fp32 row norms ----
  unsigned short* lds_Z = lds_B;
#pragma unroll
  for (int i = 0; i < 2; ++i) {
#pragma unroll
    for (int r = 0; r < 4; ++r) {
      float s2 = 0.0f;
      const int row = (i << 4) + (q << 2) + r;
#pragma unroll
      for (int j = 0; j < 4; ++j) {
        const float v = acc[i][j][r];
        s2 += v * v;
        lds_Z[row * Z_STRIDE + (w << 6) + (j << 4) + lc] = f2bf(v);
      }
      s2 += __shfl_xor(s2, 1);
      s2 += __shfl_xor(s2, 2);
      s2 += __shfl_xor(s2, 4);
      s2 += __shfl_xor(s2, 8);
      if (lc == 0) lds_part[w][row] = s2;
    }
  }
  __syncthreads();
  if (t < BM) {
    const float n2  = lds_part[0][t] + lds_part[1][t] + lds_part[2][t] + lds_part[3][t];
    const float nrm = sqrtf(n2);
    const float inv = 1.0f / fmaxf(nrm, 1e-12f);   // torch/jax normalize eps
    lds_inv[t] = inv;
    lds_z2[t]  = n2 * inv * inv;                   // == 1 unless degenerate
  }
  __syncthreads();

  // ---- GEMM2: dot(Zraw, proto_c), wave w -> protos 16w..16w+15, m-tiles 0..1 ----
  v4f acc2[2];
  acc2[0] = (v4f)(0.0f); acc2[1] = (v4f)(0.0f);
#pragma unroll
  for (int kk = 0; kk < 8; ++kk) {
    v8s za[2], pb;
#pragma unroll
    for (int i = 0; i < 2; ++i)
      za[i] = *(const v8s*)(lds_Z + ((i << 4) + lc) * Z_STRIDE + (kk << 5) + (q << 3));
    {
      const int c = (w << 4) + lc;
      const int p = ((kk << 2) + q) ^ (lc & 7);
      pb = *(const v8s*)(lds_P + c * D_PROJ + (p << 3));
    }
#pragma unroll
    for (int i = 0; i < 2; ++i)
      acc2[i] = __builtin_amdgcn_mfma_f32_16x16x32_bf16(za[i], pb, acc2[i], 0, 0, 0);
  }

  // ---- epilogue: d^2 = ||Z||^2 + ||p||^2 - 2*dot*inv ; score = -sqrt(d^2) ----
  const int c  = (w << 4) + lc;
  const float pn = pnorm2[c];
#pragma unroll
  for (int i = 0; i < 2; ++i) {
#pragma unroll
    for (int r = 0; r < 4; ++r) {
      const int row = (i << 4) + (q << 2) + r;
      const float inv = lds_inv[row];
      const float d2  = lds_z2[row] + pn - 2.0f * acc2[i][r] * inv;
      out[(row0 + row) * N_C + c] = -sqrtf(fmaxf(d2, 0.0f));
    }
  }
}

extern "C" void kernel_launch(void* const* d_in, const int* in_sizes, int n_in,
                              void* d_out, int out_size, void* d_ws, size_t ws_size,
                              hipStream_t stream) {
  const float* X      = (const float*)d_in[0];
  const float* protos = (const float*)d_in[1];
  const float* mean   = (const float*)d_in[2];
  const float* proj   = (const float*)d_in[3];
  float* out = (float*)d_out;

  unsigned short* projT  = (unsigned short*)d_ws;          // 256*1024 bf16 = 512 KB
  unsigned short* protoB = projT + D_PROJ * D_IN;          // 64*256  bf16 = 32 KB
  float*          pn2    = (float*)(protoB + N_C * D_PROJ);// 64 fp32

  prep_kernel<<<80, 256, 0, stream>>>(proj, protos, projT, protoB, pn2);
  protonet_main<<<N_ROWS / BM, 256, 0, stream>>>(X, mean, projT, protoB, pn2, out);
}

// Round 2
// 122.205 us; speedup vs baseline: 1.0301x; 1.0301x over previous
//
#include <hip/hip_runtime.h>

#define D_IN   1024
#define D_PROJ 256
#define N_C    64
#define N_ROWS 16384
#define BM     32
#define BK     64
#define A_STRIDE 72     // BK + 8 pad (bf16 elems) -> 144 B rows, uniform banks
#define Z_STRIDE 264    // D_PROJ + 8 pad -> 528 B rows

typedef float v4f __attribute__((ext_vector_type(4)));
typedef short v8s __attribute__((ext_vector_type(8)));

__device__ inline unsigned short f2bf(float f) {
  unsigned int u = __float_as_uint(f);
  u = u + 0x7fffu + ((u >> 16) & 1u);   // round-to-nearest-even
  return (unsigned short)(u >> 16);
}

__device__ inline void async16(const void* g, void* s) {
  __builtin_amdgcn_global_load_lds(
      (const __attribute__((address_space(1))) unsigned int*)g,
      (__attribute__((address_space(3))) unsigned int*)s, 16, 0, 0);
}

// ---------------------------------------------------------------------------
// Prep: projT bf16 [256][1024] (transposed), protoB bf16 [64][256], pnorm2[64]
// grid 80 x 256: blocks 0..63 transpose tiles, 64..79 protos
// ---------------------------------------------------------------------------
__global__ __launch_bounds__(256) void prep_kernel(
    const float* __restrict__ proj,      // [1024][256]
    const float* __restrict__ protos,    // [64][256]
    unsigned short* __restrict__ projT,  // [256][1024]
    unsigned short* __restrict__ protoB, // [64][256]
    float* __restrict__ pnorm2)          // [64]
{
  __shared__ float tile[64][65];
  const int b = blockIdx.x;
  const int t = threadIdx.x;
  if (b < 64) {
    const int k0 = (b & 15) * 64, n0 = (b >> 4) * 64;
    const int r = t >> 4, c4 = (t & 15) * 4;
    for (int rr = r; rr < 64; rr += 16) {
      const float4 v = *(const float4*)(proj + (k0 + rr) * D_PROJ + n0 + c4);
      tile[rr][c4 + 0] = v.x; tile[rr][c4 + 1] = v.y;
      tile[rr][c4 + 2] = v.z; tile[rr][c4 + 3] = v.w;
    }
    __syncthreads();
    const int n = t >> 2, kc = (t & 3) * 16;
    unsigned short o[16];
#pragma unroll
    for (int i = 0; i < 16; ++i) o[i] = f2bf(tile[kc + i][n]);
    unsigned short* dst = projT + (n0 + n) * D_IN + k0 + kc;
#pragma unroll
    for (int i = 0; i < 4; ++i) {
      ushort4 s4 = { o[4*i+0], o[4*i+1], o[4*i+2], o[4*i+3] };
      *(ushort4*)(dst + 4*i) = s4;
    }
  } else {
    const int w = t >> 6, l = t & 63;
    const int c = (b - 64) * 4 + w;                    // proto 0..63
    const float4 v = *(const float4*)(protos + c * D_PROJ + l * 4);
    float ss = v.x*v.x + v.y*v.y + v.z*v.z + v.w*v.w;
#pragma unroll
    for (int m = 1; m < 64; m <<= 1) ss += __shfl_xor(ss, m);
    if (l == 0) pnorm2[c] = ss;
    ushort4 o = { f2bf(v.x), f2bf(v.y), f2bf(v.z), f2bf(v.w) };
    *(ushort4*)(protoB + c * D_PROJ + l * 4) = o;
  }
}

// ---------------------------------------------------------------------------
// Main fused kernel: 32 rows/block, 512 blocks, 512 threads (8 waves)
// wave w: rg = w>>2 (row half, 16 rows), cg = w&3 (64-col group / proto group)
// 2 blocks/CU x 8 waves = 16 waves/CU for latency hiding.
// ---------------------------------------------------------------------------
__global__ __launch_bounds__(512) void protonet_main(
    const float* __restrict__ X,               // [16384][1024]
    const float* __restrict__ mean,            // [1024]
    const unsigned short* __restrict__ projT,  // [256][1024] bf16
    const unsigned short* __restrict__ protoB, // [64][256]   bf16
    const float* __restrict__ pnorm2,          // [64]
    float* __restrict__ out)                   // [16384][64]
{
  __shared__ unsigned short lds_A[BM * A_STRIDE];   // 4.6 KB, padded
  __shared__ unsigned short lds_B[D_PROJ * BK];     // 32 KB, swizzled; aliased as Z later
  __shared__ unsigned short lds_P[N_C * D_PROJ];    // 32 KB, swizzled
  __shared__ float lds_part[4][BM];
  __shared__ float lds_inv[BM];
  __shared__ float lds_z2[BM];

  const int t  = threadIdx.x;
  const int w  = t >> 6;
  const int l  = t & 63;
  const int q  = l >> 4;
  const int lc = l & 15;
  const int rg = w >> 2;      // 0..1 row group (16 rows)
  const int cg = w & 3;       // 0..3 col group (64 cols) / proto group (16)
  const int row0 = blockIdx.x * BM;

  // ---- stage protos -> LDS once (swizzled chunks: phys p holds logical p^(c&7)) ----
  {
    const int co = l >> 5;          // 0/1 within the 2-row instr
    const int p  = l & 31;
#pragma unroll
    for (int s = 0; s < 4; ++s) {
      const int c = w * 8 + s * 2 + co;
      async16(protoB + c * D_PROJ + ((p ^ (c & 7)) << 3),
              lds_P + (w * 8 + s * 2) * D_PROJ);
    }
  }

  // per-lane invariant src index for B staging:
  // instr s: row n = 32w + 8s + (l>>3), phys chunk p = l&7, logical = p^(n&7)
  const int bsrc0 = ((w << 5) + (l >> 3)) * D_IN + (((l & 7) ^ ((l >> 3) & 7)) << 3);

  // A staging invariants: thread -> row ar, float4 slot aj (1 float4/thread)
  const int ar = t >> 4;
  const int aj = t & 15;
  const float* xbase = X + (row0 + ar) * D_IN + (aj << 2);
  const float* mbase = mean + (aj << 2);
  unsigned short* aw0 = lds_A + ar * A_STRIDE + (aj << 2);

  v4f acc1[4];
#pragma unroll
  for (int j = 0; j < 4; ++j) acc1[j] = (v4f)(0.0f);

  for (int kt = 0; kt < D_IN / BK; ++kt) {
    const int k0 = kt * BK;
    // issue X loads early: latency overlaps previous tile's MFMA, drained at barrier 1
    const float4 x0 = *(const float4*)(xbase + k0);
    const float4 m0 = *(const float4*)(mbase + k0);
    __syncthreads();                       // previous compute done with LDS
    // B tile: [256][64] bf16 via global_load_lds (4 instrs/wave, 1 KB each)
#pragma unroll
    for (int s = 0; s < 4; ++s) {
      async16(projT + bsrc0 + s * (8 * D_IN) + k0,
              lds_B + (((w << 5) + (s << 3)) * BK));
    }
    // A tile: center, convert, ds_write (padded)
    {
      ushort4 o0 = { f2bf(x0.x - m0.x), f2bf(x0.y - m0.y),
                     f2bf(x0.z - m0.z), f2bf(x0.w - m0.w) };
      *(ushort4*)(aw0) = o0;
    }
    __syncthreads();                       // drains vmcnt (B) + lgkm (A)
    // compute: 2 ksteps x (1 A-frag + 4 B-frag reads + 4 MFMA)
#pragma unroll
    for (int kk = 0; kk < 2; ++kk) {
      v8s a, bf[4];
      a = *(const v8s*)(lds_A + ((rg << 4) + lc) * A_STRIDE + (kk << 5) + (q << 3));
#pragma unroll
      for (int j = 0; j < 4; ++j) {
        const int nb = (cg << 6) + (j << 4) + lc;
        const int p  = ((kk << 2) + q) ^ (lc & 7);
        bf[j] = *(const v8s*)(lds_B + nb * BK + (p << 3));
      }
#pragma unroll
      for (int j = 0; j < 4; ++j)
        acc1[j] = __builtin_amdgcn_mfma_f32_16x16x32_bf16(a, bf[j], acc1[j], 0, 0, 0);
    }
  }

  __syncthreads();                          // all reads of lds_B done
  // ---- Zraw -> LDS bf16 (reuse B region, padded stride) + fp32 row norms ----
  unsigned short* lds_Z = lds_B;
#pragma unroll
  for (int r = 0; r < 4; ++r) {
    float s2 = 0.0f;
    const int row = (rg << 4) + (q << 2) + r;
#pragma unroll
    for (int j = 0; j < 4; ++j) {
      const float v = acc1[j][r];
      s2 += v * v;
      lds_Z[row * Z_STRIDE + (cg << 6) + (j << 4) + lc] = f2bf(v);
    }
    s2 += __shfl_xor(s2, 1);
    s2 += __shfl_xor(s2, 2);
    s2 += __shfl_xor(s2, 4);
    s2 += __shfl_xor(s2, 8);
    if (lc == 0) lds_part[cg][row] = s2;
  }
  __syncthreads();
  if (t < BM) {
    const float n2  = lds_part[0][t] + lds_part[1][t] + lds_part[2][t] + lds_part[3][t];
    const float nrm = sqrtf(n2);
    const float inv = 1.0f / fmaxf(nrm, 1e-12f);   // torch/jax normalize eps
    lds_inv[t] = inv;
    lds_z2[t]  = n2 * inv * inv;                   // == 1 unless degenerate
  }
  __syncthreads();

  // ---- GEMM2: dot(Zraw, proto_c); wave (rg,pg=cg): 16 rows x 16 protos ----
  v4f acc2 = (v4f)(0.0f);
#pragma unroll
  for (int kk = 0; kk < 8; ++kk) {
    v8s za, pb;
    za = *(const v8s*)(lds_Z + ((rg << 4) + lc) * Z_STRIDE + (kk << 5) + (q << 3));
    {
      const int c = (cg << 4) + lc;
      const int p = ((kk << 2) + q) ^ (lc & 7);
      pb = *(const v8s*)(lds_P + c * D_PROJ + (p << 3));
    }
    acc2 = __builtin_amdgcn_mfma_f32_16x16x32_bf16(za, pb, acc2, 0, 0, 0);
  }

  // ---- epilogue: d^2 = ||Z||^2 + ||p||^2 - 2*dot*inv ; score = -sqrt(d^2) ----
  const int c  = (cg << 4) + lc;
  const float pn = pnorm2[c];
#pragma unroll
  for (int r = 0; r < 4; ++r) {
    const int row = (rg << 4) + (q << 2) + r;
    const float inv = lds_inv[row];
    const float d2  = lds_z2[row] + pn - 2.0f * acc2[r] * inv;
    out[(row0 + row) * N_C + c] = -sqrtf(fmaxf(d2, 0.0f));
  }
}

extern "C" void kernel_launch(void* const* d_in, const int* in_sizes, int n_in,
                              void* d_out, int out_size, void* d_ws, size_t ws_size,
                              hipStream_t stream) {
  const float* X      = (const float*)d_in[0];
  const float* protos = (const float*)d_in[1];
  const float* mean   = (const float*)d_in[2];
  const float* proj   = (const float*)d_in[3];
  float* out = (float*)d_out;

  unsigned short* projT  = (unsigned short*)d_ws;          // 256*1024 bf16 = 512 KB
  unsigned short* protoB = projT + D_PROJ * D_IN;          // 64*256  bf16 = 32 KB
  float*          pn2    = (float*)(protoB + N_C * D_PROJ);// 64 fp32

  prep_kernel<<<80, 256, 0, stream>>>(proj, protos, projT, protoB, pn2);
  protonet_main<<<N_ROWS / BM, 512, 0, stream>>>(X, mean, projT, protoB, pn2, out);
}

// Round 3
// 120.201 us; speedup vs baseline: 1.0472x; 1.0167x over previous
//
#include <hip/hip_runtime.h>

#define D_IN   1024
#define D_PROJ 256
#define N_C    64
#define N_ROWS 16384
#define BM     32
#define BK     64
#define A_STRIDE 72     // BK + 8 pad (bf16 elems) -> 144 B rows, uniform banks
#define Z_STRIDE 264    // D_PROJ + 8 pad -> 528 B rows

typedef float v4f __attribute__((ext_vector_type(4)));
typedef short v8s __attribute__((ext_vector_type(8)));

__device__ inline unsigned short f2bf(float f) {
  unsigned int u = __float_as_uint(f);
  u = u + 0x7fffu + ((u >> 16) & 1u);   // round-to-nearest-even
  return (unsigned short)(u >> 16);
}

__device__ inline void async16(const void* g, void* s) {
  __builtin_amdgcn_global_load_lds(
      (const __attribute__((address_space(1))) unsigned int*)g,
      (__attribute__((address_space(3))) unsigned int*)s, 16, 0, 0);
}

// ---------------------------------------------------------------------------
// Prep: projT bf16 [256][1024] (transposed), protoB bf16 [64][256], pnorm2[64],
//       mu_p[256] = mean @ proj (fp32)
// grid 96 x 256: blocks 0..63 transpose, 64..79 protos, 80..95 mu_p
// ---------------------------------------------------------------------------
__global__ __launch_bounds__(256) void prep_kernel(
    const float* __restrict__ proj,      // [1024][256]
    const float* __restrict__ protos,    // [64][256]
    const float* __restrict__ mean,      // [1024]
    unsigned short* __restrict__ projT,  // [256][1024]
    unsigned short* __restrict__ protoB, // [64][256]
    float* __restrict__ pnorm2,          // [64]
    float* __restrict__ mu_p)            // [256]
{
  __shared__ float tile[64][65];
  __shared__ float part[16][17];
  const int b = blockIdx.x;
  const int t = threadIdx.x;
  if (b < 64) {
    const int k0 = (b & 15) * 64, n0 = (b >> 4) * 64;
    const int r = t >> 4, c4 = (t & 15) * 4;
    for (int rr = r; rr < 64; rr += 16) {
      const float4 v = *(const float4*)(proj + (k0 + rr) * D_PROJ + n0 + c4);
      tile[rr][c4 + 0] = v.x; tile[rr][c4 + 1] = v.y;
      tile[rr][c4 + 2] = v.z; tile[rr][c4 + 3] = v.w;
    }
    __syncthreads();
    const int n = t >> 2, kc = (t & 3) * 16;
    unsigned short o[16];
#pragma unroll
    for (int i = 0; i < 16; ++i) o[i] = f2bf(tile[kc + i][n]);
    unsigned short* dst = projT + (n0 + n) * D_IN + k0 + kc;
#pragma unroll
    for (int i = 0; i < 4; ++i) {
      ushort4 s4 = { o[4*i+0], o[4*i+1], o[4*i+2], o[4*i+3] };
      *(ushort4*)(dst + 4*i) = s4;
    }
  } else if (b < 80) {
    const int w = t >> 6, l = t & 63;
    const int c = (b - 64) * 4 + w;                    // proto 0..63
    const float4 v = *(const float4*)(protos + c * D_PROJ + l * 4);
    float ss = v.x*v.x + v.y*v.y + v.z*v.z + v.w*v.w;
#pragma unroll
    for (int m = 1; m < 64; m <<= 1) ss += __shfl_xor(ss, m);
    if (l == 0) pnorm2[c] = ss;
    ushort4 o = { f2bf(v.x), f2bf(v.y), f2bf(v.z), f2bf(v.w) };
    *(ushort4*)(protoB + c * D_PROJ + l * 4) = o;
  } else {
    // mu_p: 16 blocks x 16 cols each; 16-way k-split per col
    const int b2  = b - 80;
    const int col = b2 * 16 + (t & 15);
    const int ks  = t >> 4;
    float s = 0.0f;
    const int kb = ks * 64;
#pragma unroll 4
    for (int k = 0; k < 64; ++k)
      s = fmaf(mean[kb + k], proj[(kb + k) * D_PROJ + col], s);
    part[ks][t & 15] = s;
    __syncthreads();
    if (t < 16) {
      float acc = 0.0f;
#pragma unroll
      for (int i = 0; i < 16; ++i) acc += part[i][t];
      mu_p[b2 * 16 + t] = acc;
    }
  }
}

// ---------------------------------------------------------------------------
// Main fused kernel: 32 rows/block, 512 blocks, 512 threads (8 waves)
// wave w: rg = w>>2 (row half, 16 rows), cg = w&3 (64-col / proto group)
// X is preloaded into registers (bf16) in 4 chunks, pipelined with the k-loop,
// so the k-loop's barrier vmcnt(0) drain only covers L2-resident B staging.
// ---------------------------------------------------------------------------
__global__ __launch_bounds__(512, 4) void protonet_main(
    const float* __restrict__ X,               // [16384][1024]
    const unsigned short* __restrict__ projT,  // [256][1024] bf16
    const unsigned short* __restrict__ protoB, // [64][256]   bf16
    const float* __restrict__ pnorm2,          // [64]
    const float* __restrict__ mu_p,            // [256]
    float* __restrict__ out)                   // [16384][64]
{
  __shared__ unsigned short lds_A[BM * A_STRIDE];   // 4.6 KB, padded
  __shared__ unsigned short lds_B[D_PROJ * BK];     // 32 KB, swizzled; aliased as Z later
  __shared__ unsigned short lds_P[N_C * D_PROJ];    // 32 KB, swizzled
  __shared__ float lds_part[4][BM];
  __shared__ float lds_inv[BM];
  __shared__ float lds_z2[BM];

  const int t  = threadIdx.x;
  const int w  = t >> 6;
  const int l  = t & 63;
  const int q  = l >> 4;
  const int lc = l & 15;
  const int rg = w >> 2;      // 0..1 row group (16 rows)
  const int cg = w & 3;       // 0..3 col group (64 cols) / proto group (16)
  const int row0 = blockIdx.x * BM;

  // ---- stage protos -> LDS once (swizzled chunks: phys p holds logical p^(c&7)) ----
  {
    const int co = l >> 5;          // 0/1 within the 2-row instr
    const int p  = l & 31;
#pragma unroll
    for (int s = 0; s < 4; ++s) {
      const int c = w * 8 + s * 2 + co;
      async16(protoB + c * D_PROJ + ((p ^ (c & 7)) << 3),
              lds_P + (w * 8 + s * 2) * D_PROJ);
    }
  }

  // per-lane invariant src index for B staging:
  // instr s: row n = 32w + 8s + (l>>3), phys chunk p = l&7, logical = p^(n&7)
  const int bsrc0 = ((w << 5) + (l >> 3)) * D_IN + (((l & 7) ^ ((l >> 3) & 7)) << 3);

  // A: thread owns row ar, float4 slot aj; whole row-slice preloaded to regs
  const int ar = t >> 4;
  const int aj = t & 15;
  const float* xbase = X + (row0 + ar) * D_IN + (aj << 2);
  unsigned short* aw0 = lds_A + ar * A_STRIDE + (aj << 2);

  ushort4 abf[16];     // bf16 A slices, one per k-tile (32 VGPRs)
  float4  xf[4];       // in-flight chunk

#pragma unroll
  for (int i = 0; i < 4; ++i) xf[i] = *(const float4*)(xbase + i * BK);

  v4f acc1[4];
#pragma unroll
  for (int j = 0; j < 4; ++j) acc1[j] = (v4f)(0.0f);

#pragma unroll
  for (int ch = 0; ch < 4; ++ch) {
    // convert current chunk (waits on its loads), then issue next chunk
#pragma unroll
    for (int i = 0; i < 4; ++i) {
      const float4 v = xf[i];
      ushort4 o = { f2bf(v.x), f2bf(v.y), f2bf(v.z), f2bf(v.w) };
      abf[ch * 4 + i] = o;
    }
    if (ch < 3) {
#pragma unroll
      for (int i = 0; i < 4; ++i)
        xf[i] = *(const float4*)(xbase + ((ch + 1) * 4 + i) * BK);
    }
#pragma unroll
    for (int k2 = 0; k2 < 4; ++k2) {
      const int kt = ch * 4 + k2;
      const int k0 = kt * BK;
      __syncthreads();                       // previous compute done with LDS
      // B tile: [256][64] bf16 via global_load_lds (4 instrs/wave, 1 KB each)
#pragma unroll
      for (int s = 0; s < 4; ++s) {
        async16(projT + bsrc0 + s * (8 * D_IN) + k0,
                lds_B + (((w << 5) + (s << 3)) * BK));
      }
      // A tile: ds_write from registers (no global access in hot loop)
      *(ushort4*)(aw0) = abf[kt];
      __syncthreads();                       // drains vmcnt (B) + lgkm (A)
      // compute: 2 ksteps x (1 A-frag + 4 B-frag reads + 4 MFMA)
#pragma unroll
      for (int kk = 0; kk < 2; ++kk) {
        v8s a, bf[4];
        a = *(const v8s*)(lds_A + ((rg << 4) + lc) * A_STRIDE + (kk << 5) + (q << 3));
#pragma unroll
        for (int j = 0; j < 4; ++j) {
          const int nb = (cg << 6) + (j << 4) + lc;
          const int p  = ((kk << 2) + q) ^ (lc & 7);
          bf[j] = *(const v8s*)(lds_B + nb * BK + (p << 3));
        }
#pragma unroll
        for (int j = 0; j < 4; ++j)
          acc1[j] = __builtin_amdgcn_mfma_f32_16x16x32_bf16(a, bf[j], acc1[j], 0, 0, 0);
      }
    }
  }

  __syncthreads();                          // all reads of lds_B done
  // ---- Zc = Zraw - mu_p -> LDS bf16 (reuse B region) + fp32 row norms ----
  unsigned short* lds_Z = lds_B;
  float mu[4];
#pragma unroll
  for (int j = 0; j < 4; ++j) mu[j] = mu_p[(cg << 6) + (j << 4) + lc];
#pragma unroll
  for (int r = 0; r < 4; ++r) {
    float s2 = 0.0f;
    const int row = (rg << 4) + (q << 2) + r;
#pragma unroll
    for (int j = 0; j < 4; ++j) {
      const float v = acc1[j][r] - mu[j];
      s2 += v * v;
      lds_Z[row * Z_STRIDE + (cg << 6) + (j << 4) + lc] = f2bf(v);
    }
    s2 += __shfl_xor(s2, 1);
    s2 += __shfl_xor(s2, 2);
    s2 += __shfl_xor(s2, 4);
    s2 += __shfl_xor(s2, 8);
    if (lc == 0) lds_part[cg][row] = s2;
  }
  __syncthreads();
  if (t < BM) {
    const float n2  = lds_part[0][t] + lds_part[1][t] + lds_part[2][t] + lds_part[3][t];
    const float nrm = sqrtf(n2);
    const float inv = 1.0f / fmaxf(nrm, 1e-12f);   // torch/jax normalize eps
    lds_inv[t] = inv;
    lds_z2[t]  = n2 * inv * inv;                   // == 1 unless degenerate
  }
  __syncthreads();

  // ---- GEMM2: dot(Zc, proto_c); wave (rg, pg=cg): 16 rows x 16 protos ----
  v4f acc2 = (v4f)(0.0f);
#pragma unroll
  for (int kk = 0; kk < 8; ++kk) {
    v8s za, pb;
    za = *(const v8s*)(lds_Z + ((rg << 4) + lc) * Z_STRIDE + (kk << 5) + (q << 3));
    {
      const int c = (cg << 4) + lc;
      const int p = ((kk << 2) + q) ^ (lc & 7);
      pb = *(const v8s*)(lds_P + c * D_PROJ + (p << 3));
    }
    acc2 = __builtin_amdgcn_mfma_f32_16x16x32_bf16(za, pb, acc2, 0, 0, 0);
  }

  // ---- epilogue: d^2 = ||Z||^2 + ||p||^2 - 2*dot*inv ; score = -sqrt(d^2) ----
  const int c  = (cg << 4) + lc;
  const float pn = pnorm2[c];
#pragma unroll
  for (int r = 0; r < 4; ++r) {
    const int row = (rg << 4) + (q << 2) + r;
    const float inv = lds_inv[row];
    const float d2  = lds_z2[row] + pn - 2.0f * acc2[r] * inv;
    out[(row0 + row) * N_C + c] = -sqrtf(fmaxf(d2, 0.0f));
  }
}

extern "C" void kernel_launch(void* const* d_in, const int* in_sizes, int n_in,
                              void* d_out, int out_size, void* d_ws, size_t ws_size,
                              hipStream_t stream) {
  const float* X      = (const float*)d_in[0];
  const float* protos = (const float*)d_in[1];
  const float* mean   = (const float*)d_in[2];
  const float* proj   = (const float*)d_in[3];
  float* out = (float*)d_out;

  unsigned short* projT  = (unsigned short*)d_ws;          // 256*1024 bf16 = 512 KB
  unsigned short* protoB = projT + D_PROJ * D_IN;          // 64*256  bf16 = 32 KB
  float*          pn2    = (float*)(protoB + N_C * D_PROJ);// 64 fp32
  float*          mup    = pn2 + N_C;                      // 256 fp32

  prep_kernel<<<96, 256, 0, stream>>>(proj, protos, mean, projT, protoB, pn2, mup);
  protonet_main<<<N_ROWS / BM, 512, 0, stream>>>(X, projT, protoB, pn2, mup, out);
}